// Round 3
// baseline (931.833 us; speedup 1.0000x reference)
//
#include <hip/hip_runtime.h>
#include <math.h>

#define N_NODES 50000
#define N_EDGES 800000
#define D_IN    128
#define H_DIM   256
#define L_LAYERS 3

typedef short bf16x8 __attribute__((ext_vector_type(8)));
typedef float f32x4  __attribute__((ext_vector_type(4)));

// ---------------- CSR build ----------------

__global__ __launch_bounds__(256) void zero_kernel(int* __restrict__ counts,
                                                   int* __restrict__ cursor, int n) {
    int i = blockIdx.x * 256 + threadIdx.x;
    if (i < n) { counts[i] = 0; cursor[i] = 0; }
}

__global__ __launch_bounds__(256) void hist_kernel(const int* __restrict__ dst,
                                                   int* __restrict__ counts, int e_cnt) {
    int e = blockIdx.x * 256 + threadIdx.x;
    if (e < e_cnt) atomicAdd(&counts[dst[e]], 1);
}

__global__ __launch_bounds__(1024) void scan_kernel(const int* __restrict__ counts,
                                                    int* __restrict__ offsets,
                                                    float* __restrict__ dinv, int n) {
    __shared__ int sums[1024];
    int t = threadIdx.x;
    int chunk = (n + 1023) / 1024;
    int lo = t * chunk;
    int hi = lo + chunk; if (hi > n) hi = n;
    int s = 0;
    for (int i = lo; i < hi; ++i) s += counts[i];
    sums[t] = s;
    __syncthreads();
    for (int d = 1; d < 1024; d <<= 1) {
        int v = (t >= d) ? sums[t - d] : 0;
        __syncthreads();
        sums[t] += v;
        __syncthreads();
    }
    int pre = (t == 0) ? 0 : sums[t - 1];
    for (int i = lo; i < hi; ++i) {
        int c = counts[i];
        offsets[i] = pre;
        pre += c;
        dinv[i] = rsqrtf((float)(c + 1));
    }
    if (t == 1023) offsets[n] = pre;
}

__global__ __launch_bounds__(256) void fill_kernel(const int* __restrict__ src,
                                                   const int* __restrict__ dst,
                                                   const int* __restrict__ offsets,
                                                   int* __restrict__ cursor,
                                                   const float* __restrict__ dinv,
                                                   int* __restrict__ csr_src,
                                                   float* __restrict__ csr_w, int e_cnt) {
    int e = blockIdx.x * 256 + threadIdx.x;
    if (e < e_cnt) {
        int d = dst[e];
        int pos = offsets[d] + atomicAdd(&cursor[d], 1);
        int s = src[e];
        csr_src[pos] = s;
        csr_w[pos]   = dinv[s];
    }
}

// ---------------- aggregation: wave per node, unroll-4, split-bf16 output ----------------

__device__ __forceinline__ void split1(float x, ushort& hb, ushort& lb) {
    unsigned u = __float_as_uint(x);
    hb = (ushort)(u >> 16);
    float rem = x - __uint_as_float(u & 0xFFFF0000u);
    lb = (ushort)(__float_as_uint(rem) >> 16);
}

__global__ __launch_bounds__(256) void aggregate_kernel(const float* __restrict__ h,
                                                        const int* __restrict__ offsets,
                                                        const int* __restrict__ csr_src,
                                                        const float* __restrict__ csr_w,
                                                        const float* __restrict__ dinv,
                                                        ushort* __restrict__ outh,
                                                        ushort* __restrict__ outl, int n) {
    int wave = threadIdx.x >> 6;
    int lane = threadIdx.x & 63;
    int v = blockIdx.x * 4 + wave;
    if (v >= n) return;
    int c = lane * 4;
    float dv = dinv[v];
    float4 self = *(const float4*)(h + (size_t)v * H_DIM + c);
    float4 acc;
    acc.x = dv * self.x; acc.y = dv * self.y; acc.z = dv * self.z; acc.w = dv * self.w;

    int e  = offsets[v];
    int e1 = offsets[v + 1];
    for (; e + 3 < e1; e += 4) {
        int   s0 = csr_src[e],     s1 = csr_src[e + 1];
        int   s2 = csr_src[e + 2], s3 = csr_src[e + 3];
        float w0 = csr_w[e],       w1 = csr_w[e + 1];
        float w2 = csr_w[e + 2],   w3 = csr_w[e + 3];
        float4 a = *(const float4*)(h + (size_t)s0 * H_DIM + c);
        float4 b = *(const float4*)(h + (size_t)s1 * H_DIM + c);
        float4 d = *(const float4*)(h + (size_t)s2 * H_DIM + c);
        float4 f = *(const float4*)(h + (size_t)s3 * H_DIM + c);
        acc.x += w0 * a.x + w1 * b.x + w2 * d.x + w3 * f.x;
        acc.y += w0 * a.y + w1 * b.y + w2 * d.y + w3 * f.y;
        acc.z += w0 * a.z + w1 * b.z + w2 * d.z + w3 * f.z;
        acc.w += w0 * a.w + w1 * b.w + w2 * d.w + w3 * f.w;
    }
    for (; e < e1; ++e) {
        int   s0 = csr_src[e];
        float w0 = csr_w[e];
        float4 a = *(const float4*)(h + (size_t)s0 * H_DIM + c);
        acc.x += w0 * a.x; acc.y += w0 * a.y; acc.z += w0 * a.z; acc.w += w0 * a.w;
    }
    acc.x *= dv; acc.y *= dv; acc.z *= dv; acc.w *= dv;

    ushort4 hhi, hlo;
    split1(acc.x, hhi.x, hlo.x);
    split1(acc.y, hhi.y, hlo.y);
    split1(acc.z, hhi.z, hlo.z);
    split1(acc.w, hhi.w, hlo.w);
    *(ushort4*)(outh + (size_t)v * H_DIM + c) = hhi;
    *(ushort4*)(outl + (size_t)v * H_DIM + c) = hlo;
}

// ---------------- weight pre-convert: fp32 [K,256] -> frag-linear bf16 hi/lo ----------------
// dst = base + (k>>5)*8192 + (n>>4)*512 + ((k&31)>>3)*128 + (n&15)*8 + (k&7)

#define WCONV_TOTAL 294912

__global__ __launch_bounds__(256) void wconv_kernel(const float* __restrict__ W_enc,
                                                    const float* __restrict__ W_g,
                                                    const float* __restrict__ W_out,
                                                    ushort* __restrict__ whi,
                                                    ushort* __restrict__ wlo) {
    int gid = blockIdx.x * 256 + threadIdx.x;
    if (gid >= WCONV_TOTAL) return;
    const float* src; int base, e;
    if (gid < 32768)       { src = W_enc; base = 0;      e = gid; }
    else if (gid < 229376) { src = W_g;   base = 32768;  e = gid - 32768; }
    else                   { src = W_out; base = 229376; e = gid - 229376; }
    int k = e >> 8;
    int n = e & 255;
    ushort hb, lb;
    split1(src[e], hb, lb);
    int dst = base + (k >> 5) * 8192 + (n >> 4) * 512 + ((k & 31) >> 3) * 128
            + (n & 15) * 8 + (k & 7);
    whi[dst] = hb;
    wlo[dst] = lb;
}

// ---------------- LDS-free split-bf16 MFMA GEMM ----------------
// block: 256 thr = 4 waves; tile M=64 x N=256; wave w -> cols [64w,64w+64)
// A-fragments loaded DIRECTLY from global (per-lane addresses == frag layout),
// B-fragments loaded directly from frag-linear W. No LDS, no barriers.

template <int PRESPLIT>
__global__ __launch_bounds__(256) void mfma_gemm(const float* __restrict__ Af,
                                                 const ushort* __restrict__ Ah,
                                                 const ushort* __restrict__ Al,
                                                 int K,
                                                 const ushort* __restrict__ Whi,
                                                 const ushort* __restrict__ Wlo,
                                                 const float* __restrict__ bias,
                                                 float* __restrict__ C, int n, int relu) {
    int t = threadIdx.x;
    int w = t >> 6;
    int lane = t & 63;
    int row0 = blockIdx.x * 64;
    int mrow = lane & 15;
    int koct = (lane >> 4) * 8;      // 0,8,16,24

    f32x4 acc[4][4];
#pragma unroll
    for (int mt = 0; mt < 4; ++mt)
#pragma unroll
        for (int c = 0; c < 4; ++c)
            acc[mt][c] = (f32x4)(0.0f);

    int rows[4];
#pragma unroll
    for (int mt = 0; mt < 4; ++mt) {
        int r = row0 + mt * 16 + mrow;
        rows[mt] = (r < n) ? r : (n - 1);    // clamp: dup rows, never stored
    }

    int nkc = K >> 5;
    for (int kc = 0; kc < nkc; ++kc) {
        bf16x8 ahf[4], alf[4];
        if (PRESPLIT) {
#pragma unroll
            for (int mt = 0; mt < 4; ++mt) {
                size_t o = (size_t)rows[mt] * K + kc * 32 + koct;
                ahf[mt] = *(const bf16x8*)(Ah + o);
                alf[mt] = *(const bf16x8*)(Al + o);
            }
        } else {
#pragma unroll
            for (int mt = 0; mt < 4; ++mt) {
                const float* p = Af + (size_t)rows[mt] * K + kc * 32 + koct;
                float4 a0 = *(const float4*)p;
                float4 a1 = *(const float4*)(p + 4);
                union { ushort s[8]; bf16x8 v; } H, L;
                float xs[8] = {a0.x, a0.y, a0.z, a0.w, a1.x, a1.y, a1.z, a1.w};
#pragma unroll
                for (int j = 0; j < 8; ++j) split1(xs[j], (ushort&)H.s[j], (ushort&)L.s[j]);
                ahf[mt] = H.v;
                alf[mt] = L.v;
            }
        }
        bf16x8 bh[4], bl[4];
#pragma unroll
        for (int c = 0; c < 4; ++c) {
            int nt = w * 4 + c;
            size_t o = (size_t)kc * 8192 + (nt * 64 + lane) * 8;
            bh[c] = *(const bf16x8*)(Whi + o);
            bl[c] = *(const bf16x8*)(Wlo + o);
        }
#pragma unroll
        for (int c = 0; c < 4; ++c)
#pragma unroll
            for (int mt = 0; mt < 4; ++mt) {
                acc[mt][c] = __builtin_amdgcn_mfma_f32_16x16x32_bf16(ahf[mt], bh[c], acc[mt][c], 0, 0, 0);
                acc[mt][c] = __builtin_amdgcn_mfma_f32_16x16x32_bf16(alf[mt], bh[c], acc[mt][c], 0, 0, 0);
                acc[mt][c] = __builtin_amdgcn_mfma_f32_16x16x32_bf16(ahf[mt], bl[c], acc[mt][c], 0, 0, 0);
            }
    }

    // epilogue: C/D layout col=lane&15, row=(lane>>4)*4+reg
    int colq = lane & 15;
    int rowq = (lane >> 4) * 4;
#pragma unroll
    for (int c = 0; c < 4; ++c) {
        int col = w * 64 + c * 16 + colq;
        float b = bias[col];
#pragma unroll
        for (int mt = 0; mt < 4; ++mt) {
            int rb = row0 + mt * 16 + rowq;
#pragma unroll
            for (int r = 0; r < 4; ++r) {
                int row = rb + r;
                if (row < n) {
                    float v = acc[mt][c][r] + b;
                    if (relu) v = fmaxf(v, 0.f);
                    C[(size_t)row * H_DIM + col] = v;
                }
            }
        }
    }
}

// ---------------- launch ----------------

extern "C" void kernel_launch(void* const* d_in, const int* in_sizes, int n_in,
                              void* d_out, int out_size, void* d_ws, size_t ws_size,
                              hipStream_t stream) {
    const float* x     = (const float*)d_in[0];
    const int*   ei    = (const int*)d_in[1];
    const float* W_enc = (const float*)d_in[3];
    const float* b_enc = (const float*)d_in[4];
    const float* W_g   = (const float*)d_in[5];
    const float* b_g   = (const float*)d_in[6];
    const float* W_out = (const float*)d_in[7];
    const float* b_out = (const float*)d_in[8];
    float* out = (float*)d_out;

    char* ws = (char*)d_ws;
    size_t off = 0;
    auto alloc = [&](size_t bytes) -> void* {
        void* p = ws + off;
        off = (off + bytes + 255) & ~(size_t)255;
        return p;
    };
    int*    counts  = (int*)alloc((size_t)N_NODES * 4);
    int*    offsets = (int*)alloc((size_t)(N_NODES + 1) * 4);
    int*    cursor  = (int*)alloc((size_t)N_NODES * 4);
    float*  dinv    = (float*)alloc((size_t)N_NODES * 4);
    int*    csr_src = (int*)alloc((size_t)N_EDGES * 4);
    float*  csr_w   = (float*)alloc((size_t)N_EDGES * 4);
    float*  h       = (float*)alloc((size_t)N_NODES * H_DIM * 4);
    ushort* whi     = (ushort*)alloc((size_t)WCONV_TOTAL * 2);
    ushort* wlo     = (ushort*)alloc((size_t)WCONV_TOTAL * 2);

    // agg split-bf16 scratch lives in d_out (2 x 25.6 MB == out's 51.2 MB)
    ushort* aggh = (ushort*)out;
    ushort* aggl = aggh + (size_t)N_NODES * H_DIM;

    const int* src = ei;
    const int* dst = ei + N_EDGES;

    zero_kernel<<<(N_NODES + 255) / 256, 256, 0, stream>>>(counts, cursor, N_NODES);
    hist_kernel<<<(N_EDGES + 255) / 256, 256, 0, stream>>>(dst, counts, N_EDGES);
    scan_kernel<<<1, 1024, 0, stream>>>(counts, offsets, dinv, N_NODES);
    fill_kernel<<<(N_EDGES + 255) / 256, 256, 0, stream>>>(src, dst, offsets, cursor, dinv,
                                                           csr_src, csr_w, N_EDGES);
    wconv_kernel<<<(WCONV_TOTAL + 255) / 256, 256, 0, stream>>>(W_enc, W_g, W_out, whi, wlo);

    int gemm_grid = (N_NODES + 63) / 64;
    // encoder: h = relu(x @ W_enc + b_enc), inline-split A
    mfma_gemm<0><<<gemm_grid, 256, 0, stream>>>(x, (const ushort*)nullptr, (const ushort*)nullptr,
                                                D_IN, whi, wlo, b_enc, h, N_NODES, 1);
    // 3 GCN layers: agg (pre-split) -> GEMM
    for (int l = 0; l < L_LAYERS; ++l) {
        aggregate_kernel<<<N_NODES / 4, 256, 0, stream>>>(h, offsets, csr_src, csr_w, dinv,
                                                          aggh, aggl, N_NODES);
        mfma_gemm<1><<<gemm_grid, 256, 0, stream>>>((const float*)nullptr, aggh, aggl,
                                                    H_DIM,
                                                    whi + 32768 + (size_t)l * 65536,
                                                    wlo + 32768 + (size_t)l * 65536,
                                                    b_g + (size_t)l * H_DIM, h, N_NODES, 1);
    }
    // output head (no relu), inline-split A reading h
    mfma_gemm<0><<<gemm_grid, 256, 0, stream>>>(h, (const ushort*)nullptr, (const ushort*)nullptr,
                                                H_DIM, whi + 229376, wlo + 229376,
                                                b_out, out, N_NODES, 0);
}

// Round 4
// 658.277 us; speedup vs baseline: 1.4156x; 1.4156x over previous
//
#include <hip/hip_runtime.h>
#include <math.h>

#define N_NODES 50000
#define N_EDGES 800000
#define D_IN    128
#define H_DIM   256
#define L_LAYERS 3

typedef _Float16 f16x8 __attribute__((ext_vector_type(8)));
typedef _Float16 f16x4 __attribute__((ext_vector_type(4)));
typedef float    f32x4 __attribute__((ext_vector_type(4)));

// ---------------- CSR build ----------------

__global__ __launch_bounds__(256) void zero_kernel(int* __restrict__ counts,
                                                   int* __restrict__ cursor, int n) {
    int i = blockIdx.x * 256 + threadIdx.x;
    if (i < n) { counts[i] = 0; cursor[i] = 0; }
}

__global__ __launch_bounds__(256) void hist_kernel(const int* __restrict__ dst,
                                                   int* __restrict__ counts, int e_cnt) {
    int e = blockIdx.x * 256 + threadIdx.x;
    if (e < e_cnt) atomicAdd(&counts[dst[e]], 1);
}

__global__ __launch_bounds__(1024) void scan_kernel(const int* __restrict__ counts,
                                                    int* __restrict__ offsets,
                                                    float* __restrict__ dinv, int n) {
    __shared__ int sums[1024];
    int t = threadIdx.x;
    int chunk = (n + 1023) / 1024;
    int lo = t * chunk;
    int hi = lo + chunk; if (hi > n) hi = n;
    int s = 0;
    for (int i = lo; i < hi; ++i) s += counts[i];
    sums[t] = s;
    __syncthreads();
    for (int d = 1; d < 1024; d <<= 1) {
        int v = (t >= d) ? sums[t - d] : 0;
        __syncthreads();
        sums[t] += v;
        __syncthreads();
    }
    int pre = (t == 0) ? 0 : sums[t - 1];
    for (int i = lo; i < hi; ++i) {
        int c = counts[i];
        offsets[i] = pre;
        pre += c;
        dinv[i] = rsqrtf((float)(c + 1));
    }
    if (t == 1023) offsets[n] = pre;
}

__global__ __launch_bounds__(256) void fill_kernel(const int* __restrict__ src,
                                                   const int* __restrict__ dst,
                                                   const int* __restrict__ offsets,
                                                   int* __restrict__ cursor,
                                                   const float* __restrict__ dinv,
                                                   int* __restrict__ csr_src,
                                                   float* __restrict__ csr_w, int e_cnt) {
    int e = blockIdx.x * 256 + threadIdx.x;
    if (e < e_cnt) {
        int d = dst[e];
        int pos = offsets[d] + atomicAdd(&cursor[d], 1);
        int s = src[e];
        csr_src[pos] = s;
        csr_w[pos]   = dinv[s];
    }
}

// ---------------- aggregation: fp16 gather, fp32 accumulate, fp16 out ----------------
// wave per node; lane = 4 cols (8B loads); unroll-4 for MLP

__global__ __launch_bounds__(256) void aggregate_kernel(const _Float16* __restrict__ h,
                                                        const int* __restrict__ offsets,
                                                        const int* __restrict__ csr_src,
                                                        const float* __restrict__ csr_w,
                                                        const float* __restrict__ dinv,
                                                        _Float16* __restrict__ outp, int n) {
    int wave = threadIdx.x >> 6;
    int lane = threadIdx.x & 63;
    int v = blockIdx.x * 4 + wave;
    if (v >= n) return;
    int c = lane * 4;
    float dv = dinv[v];
    f16x4 self = *(const f16x4*)(h + (size_t)v * H_DIM + c);
    float ax = dv * (float)self[0];
    float ay = dv * (float)self[1];
    float az = dv * (float)self[2];
    float aw = dv * (float)self[3];

    int e  = offsets[v];
    int e1 = offsets[v + 1];
    for (; e + 3 < e1; e += 4) {
        int   s0 = csr_src[e],     s1 = csr_src[e + 1];
        int   s2 = csr_src[e + 2], s3 = csr_src[e + 3];
        float w0 = csr_w[e],       w1 = csr_w[e + 1];
        float w2 = csr_w[e + 2],   w3 = csr_w[e + 3];
        f16x4 a = *(const f16x4*)(h + (size_t)s0 * H_DIM + c);
        f16x4 b = *(const f16x4*)(h + (size_t)s1 * H_DIM + c);
        f16x4 d = *(const f16x4*)(h + (size_t)s2 * H_DIM + c);
        f16x4 f = *(const f16x4*)(h + (size_t)s3 * H_DIM + c);
        ax += w0 * (float)a[0] + w1 * (float)b[0] + w2 * (float)d[0] + w3 * (float)f[0];
        ay += w0 * (float)a[1] + w1 * (float)b[1] + w2 * (float)d[1] + w3 * (float)f[1];
        az += w0 * (float)a[2] + w1 * (float)b[2] + w2 * (float)d[2] + w3 * (float)f[2];
        aw += w0 * (float)a[3] + w1 * (float)b[3] + w2 * (float)d[3] + w3 * (float)f[3];
    }
    for (; e < e1; ++e) {
        int   s0 = csr_src[e];
        float w0 = csr_w[e];
        f16x4 a = *(const f16x4*)(h + (size_t)s0 * H_DIM + c);
        ax += w0 * (float)a[0]; ay += w0 * (float)a[1];
        az += w0 * (float)a[2]; aw += w0 * (float)a[3];
    }
    f16x4 o;
    o[0] = (_Float16)(ax * dv);
    o[1] = (_Float16)(ay * dv);
    o[2] = (_Float16)(az * dv);
    o[3] = (_Float16)(aw * dv);
    *(f16x4*)(outp + (size_t)v * H_DIM + c) = o;
}

// ---------------- weight pre-convert: fp32 [K,256] -> frag-linear f16 hi/lo ----------------
// dst = base + (k>>5)*8192 + (n>>4)*512 + ((k&31)>>3)*128 + (n&15)*8 + (k&7)

#define WCONV_TOTAL 294912

__global__ __launch_bounds__(256) void wconv_kernel(const float* __restrict__ W_enc,
                                                    const float* __restrict__ W_g,
                                                    const float* __restrict__ W_out,
                                                    _Float16* __restrict__ whi,
                                                    _Float16* __restrict__ wlo) {
    int gid = blockIdx.x * 256 + threadIdx.x;
    if (gid >= WCONV_TOTAL) return;
    const float* src; int base, e;
    if (gid < 32768)       { src = W_enc; base = 0;      e = gid; }
    else if (gid < 229376) { src = W_g;   base = 32768;  e = gid - 32768; }
    else                   { src = W_out; base = 229376; e = gid - 229376; }
    int k = e >> 8;
    int n = e & 255;
    float x = src[e];
    _Float16 hb = (_Float16)x;
    _Float16 lb = (_Float16)(x - (float)hb);
    int dst = base + (k >> 5) * 8192 + (n >> 4) * 512 + ((k & 31) >> 3) * 128
            + (n & 15) * 8 + (k & 7);
    whi[dst] = hb;
    wlo[dst] = lb;
}

// ---------------- f16 MFMA GEMM: C[n,256] = act(A[n,K] @ W[K,256] + bias) ----------------
// block: 256 thr = 4 waves; tile M=64 x N=256; wave w -> cols [64w,64w+64)
// A fragments loaded DIRECTLY from global (f16, per-lane addr == frag layout).
// W (hi/lo split) staged per-kc into LDS via global_load_lds, read as ds_read_b128.
// AMODE 0: A fp32, inline hi/lo split (3 MFMA/tile)  — encoder
// AMODE 1: A f16 single (2 MFMA/tile: A*Wh + A*Wl)   — hidden/out layers

template <int AMODE, int OUT16>
__global__ __launch_bounds__(256, 3) void mfma_gemm(const float* __restrict__ Af,
                                                    const _Float16* __restrict__ A16,
                                                    int K,
                                                    const _Float16* __restrict__ WhG,
                                                    const _Float16* __restrict__ WlG,
                                                    const float* __restrict__ bias,
                                                    float* __restrict__ Cf,
                                                    _Float16* __restrict__ Ch,
                                                    int n, int relu) {
    __shared__ _Float16 Wh[8192];   // [nt(16)][lane(64)][j(8)] = 16 KB
    __shared__ _Float16 Wl[8192];

    int t = threadIdx.x;
    int w = t >> 6;
    int lane = t & 63;
    int row0 = blockIdx.x * 64;
    int mrow = lane & 15;
    int koct = (lane >> 4) * 8;

    f32x4 acc[4][4];
#pragma unroll
    for (int mt = 0; mt < 4; ++mt)
#pragma unroll
        for (int c = 0; c < 4; ++c)
            acc[mt][c] = (f32x4)(0.0f);

    int rows[4];
#pragma unroll
    for (int mt = 0; mt < 4; ++mt) {
        int r = row0 + mt * 16 + mrow;
        rows[mt] = (r < n) ? r : (n - 1);    // clamp: dup rows, never stored
    }

    int nkc = K >> 5;
    for (int kc = 0; kc < nkc; ++kc) {
        // ---- stage W hi/lo tile (32 KB) via async global->LDS, shared by 4 waves ----
        {
            const _Float16* gh = WhG + (size_t)kc * 8192;
            const _Float16* gl = WlG + (size_t)kc * 8192;
#pragma unroll
            for (int i = 0; i < 4; ++i) {
                int chunk = w * 4 + i;       // 16 x 1KB chunks per array
                __builtin_amdgcn_global_load_lds(
                    (const __attribute__((address_space(1))) unsigned int*)(gh + chunk * 512 + lane * 8),
                    (__attribute__((address_space(3))) unsigned int*)(&Wh[chunk * 512]),
                    16, 0, 0);
                __builtin_amdgcn_global_load_lds(
                    (const __attribute__((address_space(1))) unsigned int*)(gl + chunk * 512 + lane * 8),
                    (__attribute__((address_space(3))) unsigned int*)(&Wl[chunk * 512]),
                    16, 0, 0);
            }
        }

        // ---- A fragments direct from global ----
        f16x8 ahf[4], alf[4];
        if (AMODE == 1) {
#pragma unroll
            for (int mt = 0; mt < 4; ++mt)
                ahf[mt] = *(const f16x8*)(A16 + (size_t)rows[mt] * K + kc * 32 + koct);
        } else {
#pragma unroll
            for (int mt = 0; mt < 4; ++mt) {
                const float* p = Af + (size_t)rows[mt] * K + kc * 32 + koct;
                float4 a0 = *(const float4*)p;
                float4 a1 = *(const float4*)(p + 4);
                float xs[8] = {a0.x, a0.y, a0.z, a0.w, a1.x, a1.y, a1.z, a1.w};
                f16x8 H, L;
#pragma unroll
                for (int j = 0; j < 8; ++j) {
                    _Float16 hb = (_Float16)xs[j];
                    H[j] = hb;
                    L[j] = (_Float16)(xs[j] - (float)hb);
                }
                ahf[mt] = H;
                alf[mt] = L;
            }
        }
        __syncthreads();

        // ---- B fragments from LDS + MFMA ----
#pragma unroll
        for (int c = 0; c < 4; ++c) {
            int nt = w * 4 + c;
            f16x8 bh = *(const f16x8*)&Wh[(nt * 64 + lane) * 8];
            f16x8 bl = *(const f16x8*)&Wl[(nt * 64 + lane) * 8];
#pragma unroll
            for (int mt = 0; mt < 4; ++mt) {
                acc[mt][c] = __builtin_amdgcn_mfma_f32_16x16x32_f16(ahf[mt], bh, acc[mt][c], 0, 0, 0);
                acc[mt][c] = __builtin_amdgcn_mfma_f32_16x16x32_f16(ahf[mt], bl, acc[mt][c], 0, 0, 0);
                if (AMODE == 0)
                    acc[mt][c] = __builtin_amdgcn_mfma_f32_16x16x32_f16(alf[mt], bh, acc[mt][c], 0, 0, 0);
            }
        }
        __syncthreads();
    }

    // ---- epilogue: C/D layout col=lane&15, row=(lane>>4)*4+reg ----
    int colq = lane & 15;
    int rowq = (lane >> 4) * 4;
#pragma unroll
    for (int c = 0; c < 4; ++c) {
        int col = w * 64 + c * 16 + colq;
        float b = bias[col];
#pragma unroll
        for (int mt = 0; mt < 4; ++mt) {
            int rb = row0 + mt * 16 + rowq;
#pragma unroll
            for (int r = 0; r < 4; ++r) {
                int row = rb + r;
                if (row < n) {
                    float v = acc[mt][c][r] + b;
                    if (relu) v = fmaxf(v, 0.f);
                    if (OUT16) Ch[(size_t)row * H_DIM + col] = (_Float16)v;
                    else       Cf[(size_t)row * H_DIM + col] = v;
                }
            }
        }
    }
}

// ---------------- launch ----------------

extern "C" void kernel_launch(void* const* d_in, const int* in_sizes, int n_in,
                              void* d_out, int out_size, void* d_ws, size_t ws_size,
                              hipStream_t stream) {
    const float* x     = (const float*)d_in[0];
    const int*   ei    = (const int*)d_in[1];
    const float* W_enc = (const float*)d_in[3];
    const float* b_enc = (const float*)d_in[4];
    const float* W_g   = (const float*)d_in[5];
    const float* b_g   = (const float*)d_in[6];
    const float* W_out = (const float*)d_in[7];
    const float* b_out = (const float*)d_in[8];
    float* out = (float*)d_out;

    char* ws = (char*)d_ws;
    size_t off = 0;
    auto alloc = [&](size_t bytes) -> void* {
        void* p = ws + off;
        off = (off + bytes + 255) & ~(size_t)255;
        return p;
    };
    int*       counts  = (int*)alloc((size_t)N_NODES * 4);
    int*       offsets = (int*)alloc((size_t)(N_NODES + 1) * 4);
    int*       cursor  = (int*)alloc((size_t)N_NODES * 4);
    float*     dinv    = (float*)alloc((size_t)N_NODES * 4);
    int*       csr_src = (int*)alloc((size_t)N_EDGES * 4);
    float*     csr_w   = (float*)alloc((size_t)N_EDGES * 4);
    _Float16*  h16     = (_Float16*)alloc((size_t)N_NODES * H_DIM * 2);
    _Float16*  agg16   = (_Float16*)alloc((size_t)N_NODES * H_DIM * 2);
    _Float16*  whi     = (_Float16*)alloc((size_t)WCONV_TOTAL * 2);
    _Float16*  wlo     = (_Float16*)alloc((size_t)WCONV_TOTAL * 2);

    const int* src = ei;
    const int* dst = ei + N_EDGES;

    zero_kernel<<<(N_NODES + 255) / 256, 256, 0, stream>>>(counts, cursor, N_NODES);
    hist_kernel<<<(N_EDGES + 255) / 256, 256, 0, stream>>>(dst, counts, N_EDGES);
    scan_kernel<<<1, 1024, 0, stream>>>(counts, offsets, dinv, N_NODES);
    fill_kernel<<<(N_EDGES + 255) / 256, 256, 0, stream>>>(src, dst, offsets, cursor, dinv,
                                                           csr_src, csr_w, N_EDGES);
    wconv_kernel<<<(WCONV_TOTAL + 255) / 256, 256, 0, stream>>>(W_enc, W_g, W_out, whi, wlo);

    int gemm_grid = (N_NODES + 63) / 64;
    // encoder: h1 = relu(x @ W_enc + b_enc), fp32 A inline-split, f16 out
    mfma_gemm<0, 1><<<gemm_grid, 256, 0, stream>>>(x, (const _Float16*)nullptr, D_IN,
                                                   whi, wlo, b_enc,
                                                   (float*)nullptr, h16, N_NODES, 1);
    // 3 GCN layers
    for (int l = 0; l < L_LAYERS; ++l) {
        aggregate_kernel<<<N_NODES / 4, 256, 0, stream>>>(h16, offsets, csr_src, csr_w, dinv,
                                                          agg16, N_NODES);
        mfma_gemm<1, 1><<<gemm_grid, 256, 0, stream>>>((const float*)nullptr, agg16, H_DIM,
                                                       whi + 32768 + (size_t)l * 65536,
                                                       wlo + 32768 + (size_t)l * 65536,
                                                       b_g + (size_t)l * H_DIM,
                                                       (float*)nullptr, h16, N_NODES, 1);
    }
    // output head (no relu), f16 A, fp32 out
    mfma_gemm<1, 0><<<gemm_grid, 256, 0, stream>>>((const float*)nullptr, h16, H_DIM,
                                                   whi + 229376, wlo + 229376, b_out,
                                                   out, (_Float16*)nullptr, N_NODES, 0);
}

// Round 5
// 563.740 us; speedup vs baseline: 1.6529x; 1.1677x over previous
//
#include <hip/hip_runtime.h>
#include <math.h>

#define N_NODES 50000
#define N_EDGES 800000
#define D_IN    128
#define H_DIM   256
#define L_LAYERS 3
#define SCAN_BLOCKS ((N_NODES + 255) / 256)   // 196

typedef _Float16 f16x8 __attribute__((ext_vector_type(8)));
typedef _Float16 f16x4 __attribute__((ext_vector_type(4)));
typedef float    f32x4 __attribute__((ext_vector_type(4)));

// ---------------- CSR build ----------------

__global__ __launch_bounds__(256) void zero_kernel(int* __restrict__ counts,
                                                   int* __restrict__ cursor, int n) {
    int i = blockIdx.x * 256 + threadIdx.x;
    if (i < n) { counts[i] = 0; cursor[i] = 0; }
}

__global__ __launch_bounds__(256) void hist_kernel(const int* __restrict__ dst,
                                                   int* __restrict__ counts, int e_cnt) {
    int e = blockIdx.x * 256 + threadIdx.x;
    if (e < e_cnt) atomicAdd(&counts[dst[e]], 1);
}

// phase A: per-block sum of counts + dinv
__global__ __launch_bounds__(256) void scanA_kernel(const int* __restrict__ counts,
                                                    int* __restrict__ blocksum,
                                                    float* __restrict__ dinv, int n) {
    __shared__ int s[256];
    int t = threadIdx.x;
    int i = blockIdx.x * 256 + t;
    int v = (i < n) ? counts[i] : 0;
    if (i < n) dinv[i] = rsqrtf((float)(v + 1));
    s[t] = v;
    __syncthreads();
#pragma unroll
    for (int d = 128; d > 0; d >>= 1) {
        if (t < d) s[t] += s[t + d];
        __syncthreads();
    }
    if (t == 0) blocksum[blockIdx.x] = s[0];
}

// phase B: exclusive scan of block sums (<=256 of them) + offsets[n]
__global__ __launch_bounds__(256) void scanB_kernel(int* __restrict__ blocksum,
                                                    int* __restrict__ offsets,
                                                    int nblocks, int n, int total) {
    __shared__ int s[256];
    int t = threadIdx.x;
    int v = (t < nblocks) ? blocksum[t] : 0;
    s[t] = v;
    __syncthreads();
#pragma unroll
    for (int d = 1; d < 256; d <<= 1) {
        int x = (t >= d) ? s[t - d] : 0;
        __syncthreads();
        s[t] += x;
        __syncthreads();
    }
    if (t < nblocks) blocksum[t] = s[t] - v;   // exclusive prefix
    if (t == 0) offsets[n] = total;
}

// phase C: per-block exclusive scan + block prefix -> offsets
__global__ __launch_bounds__(256) void scanC_kernel(const int* __restrict__ counts,
                                                    const int* __restrict__ blocksum,
                                                    int* __restrict__ offsets, int n) {
    __shared__ int s[256];
    int t = threadIdx.x;
    int i = blockIdx.x * 256 + t;
    int v = (i < n) ? counts[i] : 0;
    s[t] = v;
    __syncthreads();
#pragma unroll
    for (int d = 1; d < 256; d <<= 1) {
        int x = (t >= d) ? s[t - d] : 0;
        __syncthreads();
        s[t] += x;
        __syncthreads();
    }
    if (i < n) offsets[i] = blocksum[blockIdx.x] + s[t] - v;
}

__global__ __launch_bounds__(256) void fill_kernel(const int* __restrict__ src,
                                                   const int* __restrict__ dst,
                                                   const int* __restrict__ offsets,
                                                   int* __restrict__ cursor,
                                                   const float* __restrict__ dinv,
                                                   int* __restrict__ csr_src,
                                                   float* __restrict__ csr_w, int e_cnt) {
    int e = blockIdx.x * 256 + threadIdx.x;
    if (e < e_cnt) {
        int d = dst[e];
        int pos = offsets[d] + atomicAdd(&cursor[d], 1);
        int s = src[e];
        csr_src[pos] = s;
        csr_w[pos]   = dinv[s];
    }
}

// ---------------- aggregation: fp16 gather, fp32 accumulate, fp16 out ----------------

__global__ __launch_bounds__(256) void aggregate_kernel(const _Float16* __restrict__ h,
                                                        const int* __restrict__ offsets,
                                                        const int* __restrict__ csr_src,
                                                        const float* __restrict__ csr_w,
                                                        const float* __restrict__ dinv,
                                                        _Float16* __restrict__ outp, int n) {
    int wave = threadIdx.x >> 6;
    int lane = threadIdx.x & 63;
    int v = blockIdx.x * 4 + wave;
    if (v >= n) return;
    int c = lane * 4;
    float dv = dinv[v];
    f16x4 self = *(const f16x4*)(h + (size_t)v * H_DIM + c);
    float ax = dv * (float)self[0];
    float ay = dv * (float)self[1];
    float az = dv * (float)self[2];
    float aw = dv * (float)self[3];

    int e  = offsets[v];
    int e1 = offsets[v + 1];
    for (; e + 3 < e1; e += 4) {
        int   s0 = csr_src[e],     s1 = csr_src[e + 1];
        int   s2 = csr_src[e + 2], s3 = csr_src[e + 3];
        float w0 = csr_w[e],       w1 = csr_w[e + 1];
        float w2 = csr_w[e + 2],   w3 = csr_w[e + 3];
        f16x4 a = *(const f16x4*)(h + (size_t)s0 * H_DIM + c);
        f16x4 b = *(const f16x4*)(h + (size_t)s1 * H_DIM + c);
        f16x4 d = *(const f16x4*)(h + (size_t)s2 * H_DIM + c);
        f16x4 f = *(const f16x4*)(h + (size_t)s3 * H_DIM + c);
        ax += w0 * (float)a[0] + w1 * (float)b[0] + w2 * (float)d[0] + w3 * (float)f[0];
        ay += w0 * (float)a[1] + w1 * (float)b[1] + w2 * (float)d[1] + w3 * (float)f[1];
        az += w0 * (float)a[2] + w1 * (float)b[2] + w2 * (float)d[2] + w3 * (float)f[2];
        aw += w0 * (float)a[3] + w1 * (float)b[3] + w2 * (float)d[3] + w3 * (float)f[3];
    }
    for (; e < e1; ++e) {
        int   s0 = csr_src[e];
        float w0 = csr_w[e];
        f16x4 a = *(const f16x4*)(h + (size_t)s0 * H_DIM + c);
        ax += w0 * (float)a[0]; ay += w0 * (float)a[1];
        az += w0 * (float)a[2]; aw += w0 * (float)a[3];
    }
    f16x4 o;
    o[0] = (_Float16)(ax * dv);
    o[1] = (_Float16)(ay * dv);
    o[2] = (_Float16)(az * dv);
    o[3] = (_Float16)(aw * dv);
    *(f16x4*)(outp + (size_t)v * H_DIM + c) = o;
}

// ---------------- weight pre-convert: fp32 [K,256] -> frag-linear f16 hi/lo ----------------
// dst = base + (k>>5)*8192 + (n>>4)*512 + ((k&31)>>3)*128 + (n&15)*8 + (k&7)

#define WCONV_TOTAL 294912

__global__ __launch_bounds__(256) void wconv_kernel(const float* __restrict__ W_enc,
                                                    const float* __restrict__ W_g,
                                                    const float* __restrict__ W_out,
                                                    _Float16* __restrict__ whi,
                                                    _Float16* __restrict__ wlo) {
    int gid = blockIdx.x * 256 + threadIdx.x;
    if (gid >= WCONV_TOTAL) return;
    const float* src; int base, e;
    if (gid < 32768)       { src = W_enc; base = 0;      e = gid; }
    else if (gid < 229376) { src = W_g;   base = 32768;  e = gid - 32768; }
    else                   { src = W_out; base = 229376; e = gid - 229376; }
    int k = e >> 8;
    int n = e & 255;
    float x = src[e];
    _Float16 hb = (_Float16)x;
    _Float16 lb = (_Float16)(x - (float)hb);
    int dst = base + (k >> 5) * 8192 + (n >> 4) * 512 + ((k & 31) >> 3) * 128
            + (n & 15) * 8 + (k & 7);
    whi[dst] = hb;
    wlo[dst] = lb;
}

// ---------------- f16 MFMA GEMM (unchanged from round 4) ----------------

template <int AMODE, int OUT16>
__global__ __launch_bounds__(256, 3) void mfma_gemm(const float* __restrict__ Af,
                                                    const _Float16* __restrict__ A16,
                                                    int K,
                                                    const _Float16* __restrict__ WhG,
                                                    const _Float16* __restrict__ WlG,
                                                    const float* __restrict__ bias,
                                                    float* __restrict__ Cf,
                                                    _Float16* __restrict__ Ch,
                                                    int n, int relu) {
    __shared__ _Float16 Wh[8192];
    __shared__ _Float16 Wl[8192];

    int t = threadIdx.x;
    int w = t >> 6;
    int lane = t & 63;
    int row0 = blockIdx.x * 64;
    int mrow = lane & 15;
    int koct = (lane >> 4) * 8;

    f32x4 acc[4][4];
#pragma unroll
    for (int mt = 0; mt < 4; ++mt)
#pragma unroll
        for (int c = 0; c < 4; ++c)
            acc[mt][c] = (f32x4)(0.0f);

    int rows[4];
#pragma unroll
    for (int mt = 0; mt < 4; ++mt) {
        int r = row0 + mt * 16 + mrow;
        rows[mt] = (r < n) ? r : (n - 1);
    }

    int nkc = K >> 5;
    for (int kc = 0; kc < nkc; ++kc) {
        {
            const _Float16* gh = WhG + (size_t)kc * 8192;
            const _Float16* gl = WlG + (size_t)kc * 8192;
#pragma unroll
            for (int i = 0; i < 4; ++i) {
                int chunk = w * 4 + i;
                __builtin_amdgcn_global_load_lds(
                    (const __attribute__((address_space(1))) unsigned int*)(gh + chunk * 512 + lane * 8),
                    (__attribute__((address_space(3))) unsigned int*)(&Wh[chunk * 512]),
                    16, 0, 0);
                __builtin_amdgcn_global_load_lds(
                    (const __attribute__((address_space(1))) unsigned int*)(gl + chunk * 512 + lane * 8),
                    (__attribute__((address_space(3))) unsigned int*)(&Wl[chunk * 512]),
                    16, 0, 0);
            }
        }

        f16x8 ahf[4], alf[4];
        if (AMODE == 1) {
#pragma unroll
            for (int mt = 0; mt < 4; ++mt)
                ahf[mt] = *(const f16x8*)(A16 + (size_t)rows[mt] * K + kc * 32 + koct);
        } else {
#pragma unroll
            for (int mt = 0; mt < 4; ++mt) {
                const float* p = Af + (size_t)rows[mt] * K + kc * 32 + koct;
                float4 a0 = *(const float4*)p;
                float4 a1 = *(const float4*)(p + 4);
                float xs[8] = {a0.x, a0.y, a0.z, a0.w, a1.x, a1.y, a1.z, a1.w};
                f16x8 H, L;
#pragma unroll
                for (int j = 0; j < 8; ++j) {
                    _Float16 hb = (_Float16)xs[j];
                    H[j] = hb;
                    L[j] = (_Float16)(xs[j] - (float)hb);
                }
                ahf[mt] = H;
                alf[mt] = L;
            }
        }
        __syncthreads();

#pragma unroll
        for (int c = 0; c < 4; ++c) {
            int nt = w * 4 + c;
            f16x8 bh = *(const f16x8*)&Wh[(nt * 64 + lane) * 8];
            f16x8 bl = *(const f16x8*)&Wl[(nt * 64 + lane) * 8];
#pragma unroll
            for (int mt = 0; mt < 4; ++mt) {
                acc[mt][c] = __builtin_amdgcn_mfma_f32_16x16x32_f16(ahf[mt], bh, acc[mt][c], 0, 0, 0);
                acc[mt][c] = __builtin_amdgcn_mfma_f32_16x16x32_f16(ahf[mt], bl, acc[mt][c], 0, 0, 0);
                if (AMODE == 0)
                    acc[mt][c] = __builtin_amdgcn_mfma_f32_16x16x32_f16(alf[mt], bh, acc[mt][c], 0, 0, 0);
            }
        }
        __syncthreads();
    }

    int colq = lane & 15;
    int rowq = (lane >> 4) * 4;
#pragma unroll
    for (int c = 0; c < 4; ++c) {
        int col = w * 64 + c * 16 + colq;
        float b = bias[col];
#pragma unroll
        for (int mt = 0; mt < 4; ++mt) {
            int rb = row0 + mt * 16 + rowq;
#pragma unroll
            for (int r = 0; r < 4; ++r) {
                int row = rb + r;
                if (row < n) {
                    float v = acc[mt][c][r] + b;
                    if (relu) v = fmaxf(v, 0.f);
                    if (OUT16) Ch[(size_t)row * H_DIM + col] = (_Float16)v;
                    else       Cf[(size_t)row * H_DIM + col] = v;
                }
            }
        }
    }
}

// ---------------- launch ----------------

extern "C" void kernel_launch(void* const* d_in, const int* in_sizes, int n_in,
                              void* d_out, int out_size, void* d_ws, size_t ws_size,
                              hipStream_t stream) {
    const float* x     = (const float*)d_in[0];
    const int*   ei    = (const int*)d_in[1];
    const float* W_enc = (const float*)d_in[3];
    const float* b_enc = (const float*)d_in[4];
    const float* W_g   = (const float*)d_in[5];
    const float* b_g   = (const float*)d_in[6];
    const float* W_out = (const float*)d_in[7];
    const float* b_out = (const float*)d_in[8];
    float* out = (float*)d_out;

    char* ws = (char*)d_ws;
    size_t off = 0;
    auto alloc = [&](size_t bytes) -> void* {
        void* p = ws + off;
        off = (off + bytes + 255) & ~(size_t)255;
        return p;
    };
    int*       counts   = (int*)alloc((size_t)N_NODES * 4);
    int*       offsets  = (int*)alloc((size_t)(N_NODES + 1) * 4);
    int*       cursor   = (int*)alloc((size_t)N_NODES * 4);
    float*     dinv     = (float*)alloc((size_t)N_NODES * 4);
    int*       blocksum = (int*)alloc((size_t)SCAN_BLOCKS * 4);
    int*       csr_src  = (int*)alloc((size_t)N_EDGES * 4);
    float*     csr_w    = (float*)alloc((size_t)N_EDGES * 4);
    _Float16*  h16      = (_Float16*)alloc((size_t)N_NODES * H_DIM * 2);
    _Float16*  agg16    = (_Float16*)alloc((size_t)N_NODES * H_DIM * 2);
    _Float16*  whi      = (_Float16*)alloc((size_t)WCONV_TOTAL * 2);
    _Float16*  wlo      = (_Float16*)alloc((size_t)WCONV_TOTAL * 2);

    const int* src = ei;
    const int* dst = ei + N_EDGES;

    zero_kernel<<<(N_NODES + 255) / 256, 256, 0, stream>>>(counts, cursor, N_NODES);
    hist_kernel<<<(N_EDGES + 255) / 256, 256, 0, stream>>>(dst, counts, N_EDGES);
    scanA_kernel<<<SCAN_BLOCKS, 256, 0, stream>>>(counts, blocksum, dinv, N_NODES);
    scanB_kernel<<<1, 256, 0, stream>>>(blocksum, offsets, SCAN_BLOCKS, N_NODES, N_EDGES);
    scanC_kernel<<<SCAN_BLOCKS, 256, 0, stream>>>(counts, blocksum, offsets, N_NODES);
    fill_kernel<<<(N_EDGES + 255) / 256, 256, 0, stream>>>(src, dst, offsets, cursor, dinv,
                                                           csr_src, csr_w, N_EDGES);
    wconv_kernel<<<(WCONV_TOTAL + 255) / 256, 256, 0, stream>>>(W_enc, W_g, W_out, whi, wlo);

    int gemm_grid = (N_NODES + 63) / 64;
    mfma_gemm<0, 1><<<gemm_grid, 256, 0, stream>>>(x, (const _Float16*)nullptr, D_IN,
                                                   whi, wlo, b_enc,
                                                   (float*)nullptr, h16, N_NODES, 1);
    for (int l = 0; l < L_LAYERS; ++l) {
        aggregate_kernel<<<N_NODES / 4, 256, 0, stream>>>(h16, offsets, csr_src, csr_w, dinv,
                                                          agg16, N_NODES);
        mfma_gemm<1, 1><<<gemm_grid, 256, 0, stream>>>((const float*)nullptr, agg16, H_DIM,
                                                       whi + 32768 + (size_t)l * 65536,
                                                       wlo + 32768 + (size_t)l * 65536,
                                                       b_g + (size_t)l * H_DIM,
                                                       (float*)nullptr, h16, N_NODES, 1);
    }
    mfma_gemm<1, 0><<<gemm_grid, 256, 0, stream>>>((const float*)nullptr, h16, H_DIM,
                                                   whi + 229376, wlo + 229376, b_out,
                                                   out, (_Float16*)nullptr, N_NODES, 0);
}